// Round 24
// baseline (51.580 us; speedup 1.0000x reference)
//
#include <hip/hip_runtime.h>
#include <hip/hip_fp16.h>

#define Hdim 128
#define Wdim 128
#define Cdim 64
#define HW   (Hdim * Wdim)
#define NPIX (4 * HW)     // 65536
#define NBLK (NPIX / 64)  // 1024 blocks, 64 px
#define NXCD 8
#define Hp 130            // padded dims
#define HWp (Hp * Hp)     // 16900

typedef _Float16 v8h __attribute__((ext_vector_type(8)));
typedef float    v4f __attribute__((ext_vector_type(4)));

// XCD-aware bijective swizzle (nwg % 8 == 0): consecutive logical blocks
// (which share image rows -> xt reuse) land on the SAME XCD's L2.
__device__ __forceinline__ int xcd_swizzle(int bid, int nblk) {
    return (bid % NXCD) * (nblk / NXCD) + bid / NXCD;
}

// ---------------------------------------------------------------------------
// Kernel 0: NCHW fp32 -> padded NHWC fp16 transpose + zero pad ring.
// At HBM roofline (~25 MB @ ~6 TB/s ~= 4.2us). Unchanged from R19.
// ---------------------------------------------------------------------------
__global__ __launch_bounds__(512) void transpose_kernel(
    const float* __restrict__ x,   // (B, C, H, W)
    __half* __restrict__ xt)       // (B, 130, 130, C) fp16
{
    __shared__ float tile[64][65];
    int lane = threadIdx.x & 63;
    int g    = threadIdx.x >> 6;
    int blk  = xcd_swizzle(blockIdx.x, NBLK);
    int pix0 = blk * 64;
    int b    = pix0 >> 14;
    int hw0  = pix0 & (HW - 1);
    int h    = hw0 >> 7;           // all 64 px of a block share one row
    int w0   = hw0 & 127;

    // zero the pad ring (2064 ring positions x 128 B)
    {
        int gid = blockIdx.x * 512 + threadIdx.x;   // raw id: blocks 0..32
        if (gid < 2064 * 8) {
            int rp  = gid >> 3, sub = gid & 7;
            int img = rp / 516, pos = rp - img * 516;
            int i, j;
            if (pos < 130)      { i = 0;   j = pos; }
            else if (pos < 260) { i = 129; j = pos - 130; }
            else { int p2 = pos - 260; i = 1 + (p2 >> 1); j = (p2 & 1) ? 129 : 0; }
            float4* dst = (float4*)(xt + ((size_t)img * HWp + i * Hp + j) * Cdim);
            dst[sub] = make_float4(0.f, 0.f, 0.f, 0.f);
        }
    }

#pragma unroll
    for (int i = 0; i < 8; ++i) {
        int c = g * 8 + i;
        tile[c][lane] = x[(size_t)(b * Cdim + c) * HW + hw0 + lane];
    }
    __syncthreads();
#pragma unroll
    for (int i = 0; i < 8; ++i) {
        int p = g * 8 + i;
        size_t ppos = ((size_t)b * HWp + (h + 1) * Hp + (w0 + 1 + p)) * Cdim + lane;
        xt[ppos] = (__half)tile[lane][p];
    }
}

// ---------------------------------------------------------------------------
// Kernel 1: FUSED. R24 = R23 with phase 1 reading the padded fp16 NHWC xt
// instead of NCHW f32 x: per (thread,tap) one dwordx4 covers all 8 channels
// -> 9 VMEM/wave (R23: 72 scalar dword) and the zero ring replaces ALL
// bounds masks. x is no longer read by this kernel at all.
// ---------------------------------------------------------------------------
__global__ __launch_bounds__(512) void fused_kernel(
    const float* __restrict__ p_dw,  // (C, 1, 3, 3)
    const float* __restrict__ p_pw,  // (18, C, 1, 1)
    const __half* __restrict__ xt,   // (B, 130, 130, C) fp16
    const float* __restrict__ c_dw,  // (C, 1, 3, 3)
    const float* __restrict__ c_pw,  // (C, C, 1, 1)
    float* __restrict__ out)         // (B, C, H, W)
{
    __shared__ __align__(16) unsigned char smem[26880];
    __shared__ __align__(16) unsigned int geoL[8][320];   // 10.24 KB
    __shared__ __align__(16) _Float16 cdw_h[9][64];       // 1.15 KB

    auto part_h = (_Float16 (*)[18][64])smem;    // [8][18][64] fp16, 18.4 KB
    auto accs_h = (_Float16 (*)[72])smem;        // [64][72] fp16, 9.2 KB
    auto outD   = (float (*)[69])(smem + 9216);  // [64][69] f32, 17.7 KB

    int tid  = threadIdx.x;
    int lane = tid & 63;
    int g    = tid >> 6;
    int blk  = xcd_swizzle(blockIdx.x, NBLK);
    int pix0 = blk * 64;
    int pix  = pix0 + lane;
    int w = pix & (Wdim - 1);
    int h = (pix >> 7) & (Hdim - 1);
    int b = pix >> 14;

    const char* xtB = (const char*)(xt + (size_t)b * HWp * Cdim);

    // --- phase 1: depthwise 3x3 stencil from padded fp16 xt ---------------
    // one dwordx4 per tap covers this thread's 8 channels; zero ring = pad.
    float t[8];
#pragma unroll
    for (int i = 0; i < 8; ++i) t[i] = 0.f;
    {
        int baseb = (((h + 1) * Hp) + (w + 1)) * 128 + g * 16;  // byte offset
#pragma unroll
        for (int tap = 0; tap < 9; ++tap) {
            int dh = tap / 3 - 1, dw = tap % 3 - 1;
            uint4 v4 = *(const uint4*)(xtB + (baseb + (dh * Hp + dw) * 128));
            const __half2* vv = (const __half2*)&v4;
#pragma unroll
            for (int d = 0; d < 4; ++d) {
                float2 f = __half22float2(vv[d]);
                t[2 * d]     += f.x * p_dw[(g * 8 + 2 * d)     * 9 + tap];
                t[2 * d + 1] += f.y * p_dw[(g * 8 + 2 * d + 1) * 9 + tap];
            }
        }
    }

    // --- phase 2: pointwise 64->18 partials -> LDS (fp16); stage c_dw ----
#pragma unroll
    for (int j = 0; j < 18; ++j) {
        float s = 0.f;
#pragma unroll
        for (int i = 0; i < 8; ++i)
            s += p_pw[j * Cdim + g * 8 + i] * t[i];
        part_h[g][j][lane] = (_Float16)s;
    }
    for (int idx = tid; idx < 9 * 64; idx += 512) {
        int k = idx >> 6, ch = idx & 63;
        cdw_h[k][ch] = (_Float16)c_dw[ch * 9 + k];
    }
    __syncthreads();

    // --- phase 3: geometry pass (reduce folded in) -> geoL ----------------
#pragma unroll
    for (int it = 0; it < 2; ++it) {
        int idx = tid + it * 512;
        if (idx < 9 * 64) {
            int k = idx >> 6;
            int p = idx & 63;

            float offx = 0.f, offy = 0.f;
#pragma unroll
            for (int q = 0; q < 8; ++q) {
                offx += (float)part_h[q][k][p];
                offy += (float)part_h[q][k + 9][p];
            }

            int ppix = pix0 + p;
            int pw2 = ppix & (Wdim - 1);
            int ph2 = (ppix >> 7) & (Hdim - 1);

            float px = (float)(ph2 + 1) + (float)(k / 3 - 1) + offx;
            float py = (float)(pw2 + 1) + (float)(k % 3 - 1) + offy;

            float fx = floorf(px), fy = floorf(py);
            float ltx = fminf(fmaxf(fx, 0.f), 129.f);
            float lty = fminf(fmaxf(fy, 0.f), 129.f);
            float rbx = fminf(fmaxf(fx + 1.f, 0.f), 129.f);
            float rby = fminf(fmaxf(fy + 1.f, 0.f), 129.f);
            float pxc = fminf(fmaxf(px, 0.f), 129.f);
            float pyc = fminf(fmaxf(py, 0.f), 129.f);

            float glt = (1.f + ltx - pxc) * (1.f + lty - pyc);
            float grb = (1.f - rbx + pxc) * (1.f - rby + pyc);
            float glb = (1.f + ltx - pxc) * (1.f - rby + pyc);
            float grt = (1.f - rbx + pxc) * (1.f + lty - pyc);

            int ix0 = (int)ltx, iy0 = (int)lty, ix1 = (int)rbx, iy1 = (int)rby;

            unsigned int bb1, bb2;
            if (iy1 == iy0 + 1) {
                bb1 = (unsigned int)(ix0 * Hp + iy0) << 7;  // byte offset
                bb2 = (unsigned int)(ix1 * Hp + iy0) << 7;
            } else {
                glt = glb = grt = grb = 0.f;   // both cols on zero ring
                bb1 = bb2 = 0;
            }

            __half2 wr0 = __floats2half2_rn(glt, glb);   // row ix0: (col0, col1)
            __half2 wr1 = __floats2half2_rn(grt, grb);   // row ix1: (col0, col1)
            uint4 pk;
            pk.x = bb1;
            pk.y = bb2;
            pk.z = *(const unsigned int*)&wr0;
            pk.w = *(const unsigned int*)&wr1;
            *(uint4*)&geoL[p >> 3][(k * 8 + (p & 7)) * 4] = pk;
        }
    }
    __syncthreads();   // geoL + cdw_h ready; part region now dead

    // --- phase 4: corner-parallel sampling --------------------------------
    int gu  = __builtin_amdgcn_readfirstlane(g);
    int pk_ = lane >> 5;             // which of the 2 pairs this iteration
    int sub = lane & 31;
    int r_  = sub >> 4;              // corner row (0 = ix0, 1 = ix1)
    int s16 = sub & 15;
    int cb  = s16 & 7;               // channel block: ch cb*8 .. cb*8+7
    int c_  = s16 >> 3;              // corner col (0 = iy0, 1 = iy0+1)
    int vsub = s16 * 16;             // byte within the 256B row window

    const char* geoB = (const char*)&geoL[0][0];
    int addrB = gu * 1280 + pk_ * 16 + r_ * 4;        // base dword
    int addrW = addrB + 8 + c_ * 2;                   // weight u16 (has r_*4)
    const char* cdwB = (const char*)&cdw_h[0][0] + cb * 16;

    __half2 acc[4][4];               // [q][dword] static-indexed
#pragma unroll
    for (int q = 0; q < 4; ++q)
#pragma unroll
        for (int d = 0; d < 4; ++d) acc[q][d] = __floats2half2_rn(0.f, 0.f);

#pragma unroll
    for (int k = 0; k < 9; ++k) {
        const __half2* wkp = (const __half2*)(cdwB + k * 128);  // 8 ch weights
        __half2 wkA = wkp[0], wkB = wkp[1], wkC = wkp[2], wkD = wkp[3];
#pragma unroll
        for (int q = 0; q < 4; ++q) {
            const int imm = (k * 8 + 2 * q) * 16;     // entry (k, 2q+pk)
            unsigned int bb = *(const unsigned int*)(geoB + addrB + imm);
            unsigned short wu = *(const unsigned short*)(geoB + addrW + imm);
            uint4 v4 = *(const uint4*)(xtB + (bb + (unsigned int)vsub));
            __half2 w2 = __half2half2(__ushort_as_half(wu));
            const __half2* vv = (const __half2*)&v4;
            acc[q][0] = __hfma2(wkA, __hmul2(w2, vv[0]), acc[q][0]);
            acc[q][1] = __hfma2(wkB, __hmul2(w2, vv[1]), acc[q][1]);
            acc[q][2] = __hfma2(wkC, __hmul2(w2, vv[2]), acc[q][2]);
            acc[q][3] = __hfma2(wkD, __hmul2(w2, vv[3]), acc[q][3]);
        }
    }

    // 4-corner reduce (commutes with k-sum): xor 8 (col), xor 16 (row)
#pragma unroll
    for (int q = 0; q < 4; ++q) {
#pragma unroll
        for (int d = 0; d < 4; ++d) {
            int v = *(int*)&acc[q][d];
            int o = __shfl_xor(v, 8);
            __half2 tmp = __hadd2(acc[q][d], *(__half2*)&o);
            int v2 = *(int*)&tmp;
            int o2 = __shfl_xor(v2, 16);
            acc[q][d] = __hadd2(tmp, *(__half2*)&o2);
        }
    }
    if ((lane & 24) == 0) {          // r=0,c=0 lanes: 0-7 (pk0), 32-39 (pk1)
#pragma unroll
        for (int q = 0; q < 4; ++q) {
            int i = 2 * q + pk_;
            uint4 st;
            st.x = *(unsigned int*)&acc[q][0];
            st.y = *(unsigned int*)&acc[q][1];
            st.z = *(unsigned int*)&acc[q][2];
            st.w = *(unsigned int*)&acc[q][3];
            *(uint4*)&accs_h[gu * 8 + i][cb * 8] = st;
        }
    }
    __syncthreads();

    // --- phase 5: MFMA pointwise ------------------------------------------
    {
        int pb = gu & 3;
        int ob = gu >> 2;
        int lr = lane & 15;
        int lg = lane >> 4;

        const v8h a0 = *(const v8h*)&accs_h[pb * 16 + lr][lg * 8];
        const v8h a1 = *(const v8h*)&accs_h[pb * 16 + lr][32 + lg * 8];

        v4f d0 = {0.f, 0.f, 0.f, 0.f}, d1 = {0.f, 0.f, 0.f, 0.f};
#pragma unroll
        for (int t2 = 0; t2 < 2; ++t2) {
            int oc = ob * 32 + t2 * 16 + lr;
            const float* wr = c_pw + oc * Cdim + lg * 8;
            v8h b0, b1;
#pragma unroll
            for (int j = 0; j < 8; ++j) {
                b0[j] = (_Float16)wr[j];
                b1[j] = (_Float16)wr[32 + j];
            }
            if (t2 == 0) {
                d0 = __builtin_amdgcn_mfma_f32_16x16x32_f16(a0, b0, d0, 0, 0, 0);
                d0 = __builtin_amdgcn_mfma_f32_16x16x32_f16(a1, b1, d0, 0, 0, 0);
            } else {
                d1 = __builtin_amdgcn_mfma_f32_16x16x32_f16(a0, b0, d1, 0, 0, 0);
                d1 = __builtin_amdgcn_mfma_f32_16x16x32_f16(a1, b1, d1, 0, 0, 0);
            }
        }

#pragma unroll
        for (int r = 0; r < 4; ++r) {
            outD[pb * 16 + lg * 4 + r][ob * 32 + lr]      = d0[r];
            outD[pb * 16 + lg * 4 + r][ob * 32 + 16 + lr] = d1[r];
        }
    }
    __syncthreads();

    // --- phase 6: coalesced NCHW store ------------------------------------
    int hw = pix & (HW - 1);
    size_t obase = (size_t)b * Cdim * HW + hw;
#pragma unroll
    for (int i = 0; i < 8; ++i)
        out[obase + (size_t)(gu * 8 + i) * HW] = outD[lane][gu * 8 + i];
}

extern "C" void kernel_launch(void* const* d_in, const int* in_sizes, int n_in,
                              void* d_out, int out_size, void* d_ws, size_t ws_size,
                              hipStream_t stream) {
    const float* x    = (const float*)d_in[0];
    const float* p_dw = (const float*)d_in[1];
    const float* p_pw = (const float*)d_in[2];
    const float* c_dw = (const float*)d_in[3];
    const float* c_pw = (const float*)d_in[4];
    float* out = (float*)d_out;

    __half* xt = (__half*)d_ws;   // 8.65 MB padded NHWC fp16

    transpose_kernel<<<dim3(NBLK), dim3(512), 0, stream>>>(x, xt);
    fused_kernel<<<dim3(NBLK), dim3(512), 0, stream>>>(p_dw, p_pw, xt, c_dw, c_pw, out);
}

// Round 25
// 49.046 us; speedup vs baseline: 1.0517x; 1.0517x over previous
//
#include <hip/hip_runtime.h>
#include <hip/hip_fp16.h>

#define Hdim 128
#define Wdim 128
#define Cdim 64
#define HW   (Hdim * Wdim)
#define NPIX (4 * HW)     // 65536
#define NBLK (NPIX / 64)  // 1024 blocks, 64 px
#define NXCD 8
#define Hp 130            // padded dims
#define HWp (Hp * Hp)     // 16900

typedef _Float16 v8h __attribute__((ext_vector_type(8)));
typedef float    v4f __attribute__((ext_vector_type(4)));

// XCD-aware bijective swizzle (nwg % 8 == 0): consecutive logical blocks
// (which share image rows -> xt reuse) land on the SAME XCD's L2.
__device__ __forceinline__ int xcd_swizzle(int bid, int nblk) {
    return (bid % NXCD) * (nblk / NXCD) + bid / NXCD;
}

// ---------------------------------------------------------------------------
// Kernel 0: NCHW fp32 -> padded NHWC fp16 transpose + zero pad ring.
// At HBM roofline (~25 MB @ ~6 TB/s ~= 4.2us).
// ---------------------------------------------------------------------------
__global__ __launch_bounds__(512) void transpose_kernel(
    const float* __restrict__ x,   // (B, C, H, W)
    __half* __restrict__ xt)       // (B, 130, 130, C) fp16
{
    __shared__ float tile[64][65];
    int lane = threadIdx.x & 63;
    int g    = threadIdx.x >> 6;
    int blk  = xcd_swizzle(blockIdx.x, NBLK);
    int pix0 = blk * 64;
    int b    = pix0 >> 14;
    int hw0  = pix0 & (HW - 1);
    int h    = hw0 >> 7;           // all 64 px of a block share one row
    int w0   = hw0 & 127;

    // zero the pad ring (2064 ring positions x 128 B)
    {
        int gid = blockIdx.x * 512 + threadIdx.x;   // raw id: blocks 0..32
        if (gid < 2064 * 8) {
            int rp  = gid >> 3, sub = gid & 7;
            int img = rp / 516, pos = rp - img * 516;
            int i, j;
            if (pos < 130)      { i = 0;   j = pos; }
            else if (pos < 260) { i = 129; j = pos - 130; }
            else { int p2 = pos - 260; i = 1 + (p2 >> 1); j = (p2 & 1) ? 129 : 0; }
            float4* dst = (float4*)(xt + ((size_t)img * HWp + i * Hp + j) * Cdim);
            dst[sub] = make_float4(0.f, 0.f, 0.f, 0.f);
        }
    }

#pragma unroll
    for (int i = 0; i < 8; ++i) {
        int c = g * 8 + i;
        tile[c][lane] = x[(size_t)(b * Cdim + c) * HW + hw0 + lane];
    }
    __syncthreads();
#pragma unroll
    for (int i = 0; i < 8; ++i) {
        int p = g * 8 + i;
        size_t ppos = ((size_t)b * HWp + (h + 1) * Hp + (w0 + 1 + p)) * Cdim + lane;
        xt[ppos] = (__half)tile[lane][p];
    }
}

// ---------------------------------------------------------------------------
// Kernel 1: FUSED (= R23, the best configuration).
//  - phase 1 stencil reads NCHW f32 x: fully coalesced, line-optimal
//    (R24's NHWC dwordx4 variant doubled the line count and regressed).
//  - corner-parallel sampling: one global_load_dwordx4 per (k,q) serves two
//    pairs' 512B; per-corner partials reduce ONCE at the end via shfl_xor.
//  - geo in LDS (16B/entry), MFMA pointwise epilogue.
// ---------------------------------------------------------------------------
__global__ __launch_bounds__(512) void fused_kernel(
    const float* __restrict__ x,     // (B, C, H, W)
    const float* __restrict__ p_dw,  // (C, 1, 3, 3)
    const float* __restrict__ p_pw,  // (18, C, 1, 1)
    const __half* __restrict__ xt,   // (B, 130, 130, C) fp16
    const float* __restrict__ c_dw,  // (C, 1, 3, 3)
    const float* __restrict__ c_pw,  // (C, C, 1, 1)
    float* __restrict__ out)         // (B, C, H, W)
{
    __shared__ __align__(16) unsigned char smem[26880];
    __shared__ __align__(16) unsigned int geoL[8][320];   // 10.24 KB
    __shared__ __align__(16) _Float16 cdw_h[9][64];       // 1.15 KB

    auto part_h = (_Float16 (*)[18][64])smem;    // [8][18][64] fp16, 18.4 KB
    auto accs_h = (_Float16 (*)[72])smem;        // [64][72] fp16, 9.2 KB
    auto outD   = (float (*)[69])(smem + 9216);  // [64][69] f32, 17.7 KB

    int tid  = threadIdx.x;
    int lane = tid & 63;
    int g    = tid >> 6;
    int blk  = xcd_swizzle(blockIdx.x, NBLK);
    int pix0 = blk * 64;
    int pix  = pix0 + lane;
    int w = pix & (Wdim - 1);
    int h = (pix >> 7) & (Hdim - 1);
    int b = pix >> 14;

    // --- phase 1: depthwise 3x3 stencil from x (masks hoisted) -----------
    int   off9[9];
    float msk9[9];
#pragma unroll
    for (int dh = -1; dh <= 1; ++dh) {
#pragma unroll
        for (int dw = -1; dw <= 1; ++dw) {
            int tap = (dh + 1) * 3 + (dw + 1);
            int hh = h + dh, ww = w + dw;
            bool ok = (hh >= 0) & (hh < Hdim) & (ww >= 0) & (ww < Wdim);
            off9[tap] = ok ? hh * Wdim + ww : 0;
            msk9[tap] = ok ? 1.f : 0.f;
        }
    }

    float t[8];
#pragma unroll
    for (int i = 0; i < 8; ++i) {
        int c = g * 8 + i;              // wave-uniform
        const float* xb0 = x + (size_t)(b * Cdim + c) * HW;
        float s = 0.f;
#pragma unroll
        for (int tap = 0; tap < 9; ++tap) {
            float v = xb0[off9[tap]] * msk9[tap];
            s += v * p_dw[c * 9 + tap];
        }
        t[i] = s;
    }

    // --- phase 2: pointwise 64->18 partials -> LDS (fp16); stage c_dw ----
#pragma unroll
    for (int j = 0; j < 18; ++j) {
        float s = 0.f;
#pragma unroll
        for (int i = 0; i < 8; ++i)
            s += p_pw[j * Cdim + g * 8 + i] * t[i];
        part_h[g][j][lane] = (_Float16)s;
    }
    for (int idx = tid; idx < 9 * 64; idx += 512) {
        int k = idx >> 6, ch = idx & 63;
        cdw_h[k][ch] = (_Float16)c_dw[ch * 9 + k];
    }
    __syncthreads();

    // --- phase 3: geometry pass (reduce folded in) -> geoL ----------------
#pragma unroll
    for (int it = 0; it < 2; ++it) {
        int idx = tid + it * 512;
        if (idx < 9 * 64) {
            int k = idx >> 6;
            int p = idx & 63;

            float offx = 0.f, offy = 0.f;
#pragma unroll
            for (int q = 0; q < 8; ++q) {
                offx += (float)part_h[q][k][p];
                offy += (float)part_h[q][k + 9][p];
            }

            int ppix = pix0 + p;
            int pw2 = ppix & (Wdim - 1);
            int ph2 = (ppix >> 7) & (Hdim - 1);

            float px = (float)(ph2 + 1) + (float)(k / 3 - 1) + offx;
            float py = (float)(pw2 + 1) + (float)(k % 3 - 1) + offy;

            float fx = floorf(px), fy = floorf(py);
            float ltx = fminf(fmaxf(fx, 0.f), 129.f);
            float lty = fminf(fmaxf(fy, 0.f), 129.f);
            float rbx = fminf(fmaxf(fx + 1.f, 0.f), 129.f);
            float rby = fminf(fmaxf(fy + 1.f, 0.f), 129.f);
            float pxc = fminf(fmaxf(px, 0.f), 129.f);
            float pyc = fminf(fmaxf(py, 0.f), 129.f);

            float glt = (1.f + ltx - pxc) * (1.f + lty - pyc);
            float grb = (1.f - rbx + pxc) * (1.f - rby + pyc);
            float glb = (1.f + ltx - pxc) * (1.f - rby + pyc);
            float grt = (1.f - rbx + pxc) * (1.f + lty - pyc);

            int ix0 = (int)ltx, iy0 = (int)lty, ix1 = (int)rbx, iy1 = (int)rby;

            unsigned int bb1, bb2;
            if (iy1 == iy0 + 1) {
                bb1 = (unsigned int)(ix0 * Hp + iy0) << 7;  // byte offset
                bb2 = (unsigned int)(ix1 * Hp + iy0) << 7;
            } else {
                glt = glb = grt = grb = 0.f;   // both cols on zero ring
                bb1 = bb2 = 0;
            }

            __half2 wr0 = __floats2half2_rn(glt, glb);   // row ix0: (col0, col1)
            __half2 wr1 = __floats2half2_rn(grt, grb);   // row ix1: (col0, col1)
            uint4 pk;
            pk.x = bb1;
            pk.y = bb2;
            pk.z = *(const unsigned int*)&wr0;
            pk.w = *(const unsigned int*)&wr1;
            *(uint4*)&geoL[p >> 3][(k * 8 + (p & 7)) * 4] = pk;
        }
    }
    __syncthreads();   // geoL + cdw_h ready; part region now dead

    // --- phase 4: corner-parallel sampling --------------------------------
    int gu  = __builtin_amdgcn_readfirstlane(g);
    int pk_ = lane >> 5;             // which of the 2 pairs this iteration
    int sub = lane & 31;
    int r_  = sub >> 4;              // corner row (0 = ix0, 1 = ix1)
    int s16 = sub & 15;
    int cb  = s16 & 7;               // channel block: ch cb*8 .. cb*8+7
    int c_  = s16 >> 3;              // corner col (0 = iy0, 1 = iy0+1)
    int vsub = s16 * 16;             // byte within the 256B row window

    const char* geoB = (const char*)&geoL[0][0];
    int addrB = gu * 1280 + pk_ * 16 + r_ * 4;        // base dword
    int addrW = addrB + 8 + c_ * 2;                   // weight u16 (has r_*4)
    const char* cdwB = (const char*)&cdw_h[0][0] + cb * 16;
    const char* xbC  = (const char*)(xt + (size_t)b * HWp * Cdim);

    __half2 acc[4][4];               // [q][dword] static-indexed
#pragma unroll
    for (int q = 0; q < 4; ++q)
#pragma unroll
        for (int d = 0; d < 4; ++d) acc[q][d] = __floats2half2_rn(0.f, 0.f);

#pragma unroll
    for (int k = 0; k < 9; ++k) {
        const __half2* wkp = (const __half2*)(cdwB + k * 128);  // 8 ch weights
        __half2 wkA = wkp[0], wkB = wkp[1], wkC = wkp[2], wkD = wkp[3];
#pragma unroll
        for (int q = 0; q < 4; ++q) {
            const int imm = (k * 8 + 2 * q) * 16;     // entry (k, 2q+pk)
            unsigned int bb = *(const unsigned int*)(geoB + addrB + imm);
            unsigned short wu = *(const unsigned short*)(geoB + addrW + imm);
            uint4 v4 = *(const uint4*)(xbC + (bb + (unsigned int)vsub));
            __half2 w2 = __half2half2(__ushort_as_half(wu));
            const __half2* vv = (const __half2*)&v4;
            acc[q][0] = __hfma2(wkA, __hmul2(w2, vv[0]), acc[q][0]);
            acc[q][1] = __hfma2(wkB, __hmul2(w2, vv[1]), acc[q][1]);
            acc[q][2] = __hfma2(wkC, __hmul2(w2, vv[2]), acc[q][2]);
            acc[q][3] = __hfma2(wkD, __hmul2(w2, vv[3]), acc[q][3]);
        }
    }

    // 4-corner reduce (commutes with k-sum): xor 8 (col), xor 16 (row)
#pragma unroll
    for (int q = 0; q < 4; ++q) {
#pragma unroll
        for (int d = 0; d < 4; ++d) {
            int v = *(int*)&acc[q][d];
            int o = __shfl_xor(v, 8);
            __half2 tmp = __hadd2(acc[q][d], *(__half2*)&o);
            int v2 = *(int*)&tmp;
            int o2 = __shfl_xor(v2, 16);
            acc[q][d] = __hadd2(tmp, *(__half2*)&o2);
        }
    }
    if ((lane & 24) == 0) {          // r=0,c=0 lanes: 0-7 (pk0), 32-39 (pk1)
#pragma unroll
        for (int q = 0; q < 4; ++q) {
            int i = 2 * q + pk_;
            uint4 st;
            st.x = *(unsigned int*)&acc[q][0];
            st.y = *(unsigned int*)&acc[q][1];
            st.z = *(unsigned int*)&acc[q][2];
            st.w = *(unsigned int*)&acc[q][3];
            *(uint4*)&accs_h[gu * 8 + i][cb * 8] = st;
        }
    }
    __syncthreads();

    // --- phase 5: MFMA pointwise ------------------------------------------
    {
        int pb = gu & 3;
        int ob = gu >> 2;
        int lr = lane & 15;
        int lg = lane >> 4;

        const v8h a0 = *(const v8h*)&accs_h[pb * 16 + lr][lg * 8];
        const v8h a1 = *(const v8h*)&accs_h[pb * 16 + lr][32 + lg * 8];

        v4f d0 = {0.f, 0.f, 0.f, 0.f}, d1 = {0.f, 0.f, 0.f, 0.f};
#pragma unroll
        for (int t2 = 0; t2 < 2; ++t2) {
            int oc = ob * 32 + t2 * 16 + lr;
            const float* wr = c_pw + oc * Cdim + lg * 8;
            v8h b0, b1;
#pragma unroll
            for (int j = 0; j < 8; ++j) {
                b0[j] = (_Float16)wr[j];
                b1[j] = (_Float16)wr[32 + j];
            }
            if (t2 == 0) {
                d0 = __builtin_amdgcn_mfma_f32_16x16x32_f16(a0, b0, d0, 0, 0, 0);
                d0 = __builtin_amdgcn_mfma_f32_16x16x32_f16(a1, b1, d0, 0, 0, 0);
            } else {
                d1 = __builtin_amdgcn_mfma_f32_16x16x32_f16(a0, b0, d1, 0, 0, 0);
                d1 = __builtin_amdgcn_mfma_f32_16x16x32_f16(a1, b1, d1, 0, 0, 0);
            }
        }

#pragma unroll
        for (int r = 0; r < 4; ++r) {
            outD[pb * 16 + lg * 4 + r][ob * 32 + lr]      = d0[r];
            outD[pb * 16 + lg * 4 + r][ob * 32 + 16 + lr] = d1[r];
        }
    }
    __syncthreads();

    // --- phase 6: coalesced NCHW store ------------------------------------
    int hw = pix & (HW - 1);
    size_t obase = (size_t)b * Cdim * HW + hw;
#pragma unroll
    for (int i = 0; i < 8; ++i)
        out[obase + (size_t)(gu * 8 + i) * HW] = outD[lane][gu * 8 + i];
}

extern "C" void kernel_launch(void* const* d_in, const int* in_sizes, int n_in,
                              void* d_out, int out_size, void* d_ws, size_t ws_size,
                              hipStream_t stream) {
    const float* x    = (const float*)d_in[0];
    const float* p_dw = (const float*)d_in[1];
    const float* p_pw = (const float*)d_in[2];
    const float* c_dw = (const float*)d_in[3];
    const float* c_pw = (const float*)d_in[4];
    float* out = (float*)d_out;

    __half* xt = (__half*)d_ws;   // 8.65 MB padded NHWC fp16

    transpose_kernel<<<dim3(NBLK), dim3(512), 0, stream>>>(x, xt);
    fused_kernel<<<dim3(NBLK), dim3(512), 0, stream>>>(x, p_dw, p_pw, xt, c_dw, c_pw, out);
}